// Round 3
// baseline (123.684 us; speedup 1.0000x reference)
//
#include <hip/hip_runtime.h>
#include <hip/hip_bf16.h>

typedef __attribute__((ext_vector_type(8))) short bf16x8;     // 8 bf16 = 4 VGPRs (MFMA A/B operand)
typedef __attribute__((ext_vector_type(4))) float f32x4;      // MFMA C/D
typedef __attribute__((ext_vector_type(8))) unsigned short ushort8;
typedef __attribute__((ext_vector_type(4))) unsigned short ushort4v;

constexpr int BB = 4096;   // batch B
constexpr int D  = 256;    // feature dim
constexpr int R2 = 8192;   // 2B rows of z
constexpr int NSPLIT = 16; // column splits of the sim reduction (512 cols per block)
constexpr int CT = 64;     // columns staged per LDS tile
constexpr int NT = (R2 / NSPLIT) / CT;  // 8 tiles per block
constexpr float SQRT2 = 1.41421356237309515f;
constexpr float E2 = 7.38905609893065f;  // exp(2) == exp(diag sim)

__device__ __forceinline__ unsigned short f2bf(float f) {
    __hip_bfloat16 h = __float2bfloat16(f);
    return *reinterpret_cast<unsigned short*>(&h);
}

// Kernel A: L2-normalize rows, scale by sqrt(2), store bf16 z[8192][256]; pos[k] = 2*cos(xi_k, xj_k).
// One wave per pair k.
__global__ __launch_bounds__(256) void norm_kernel(const float* __restrict__ xi,
                                                   const float* __restrict__ xj,
                                                   unsigned short* __restrict__ z,
                                                   float* __restrict__ pos) {
    const int wid = threadIdx.x >> 6, lane = threadIdx.x & 63;
    const int k = blockIdx.x * 4 + wid;
    const float4* a4 = reinterpret_cast<const float4*>(xi + (size_t)k * D);
    const float4* b4 = reinterpret_cast<const float4*>(xj + (size_t)k * D);
    float4 a = a4[lane], b = b4[lane];
    float ssi = a.x*a.x + a.y*a.y + a.z*a.z + a.w*a.w;
    float ssj = b.x*b.x + b.y*b.y + b.z*b.z + b.w*b.w;
    float dot = a.x*b.x + a.y*b.y + a.z*b.z + a.w*b.w;
#pragma unroll
    for (int off = 32; off; off >>= 1) {
        ssi += __shfl_xor(ssi, off);
        ssj += __shfl_xor(ssj, off);
        dot += __shfl_xor(dot, off);
    }
    const float inv_i = 1.0f / fmaxf(sqrtf(ssi), 1e-12f);
    const float inv_j = 1.0f / fmaxf(sqrtf(ssj), 1e-12f);
    const float si = inv_i * SQRT2, sj = inv_j * SQRT2;
    ushort4v zi = { f2bf(a.x*si), f2bf(a.y*si), f2bf(a.z*si), f2bf(a.w*si) };
    ushort4v zj = { f2bf(b.x*sj), f2bf(b.y*sj), f2bf(b.z*sj), f2bf(b.w*sj) };
    *reinterpret_cast<ushort4v*>(z + (size_t)k * D + lane*4)        = zi;
    *reinterpret_cast<ushort4v*>(z + (size_t)(k+BB) * D + lane*4)   = zj;
    if (lane == 0) pos[k] = dot * inv_i * inv_j * 2.0f;
}

// Kernel B: partial[split][r] = sum over this split's 512 columns c of exp(z_r . z_c).
// Block: 4 waves x 64 rows = 256 rows. Col tiles of 64 double-buffered in LDS,
// staged through registers one tile ahead (global-load latency hidden behind compute).
// LDS is unpadded; 16B chunks XOR-swizzled by (row&7) -> uniform bank load, no conflicts.
__global__ __launch_bounds__(256, 2) void sim_kernel(const unsigned short* __restrict__ z,
                                                     float* __restrict__ partial) {
    __shared__ unsigned short tb[2][CT * D];   // 2 x 32 KB
    const int tid = threadIdx.x;
    const int wid = tid >> 6, lane = tid & 63;
    const int lrow = lane & 15, quad = lane >> 4;
    const int r0 = blockIdx.x * 256 + wid * 64;       // this wave's 64 rows
    const int cbase = blockIdx.y * (R2 / NSPLIT);

    // Staging indices for this thread's 8 chunks (fixed across tiles).
    // Chunk L = i*256 + tid -> (row r = L>>5, logical 16B-chunk cl = L&31),
    // stored at physical chunk cl ^ (r&7).
    // A fragments: this wave's 64 rows x full K=256 in registers (128 VGPRs).
    bf16x8 afrag[4][8];
#pragma unroll
    for (int m = 0; m < 4; ++m)
#pragma unroll
        for (int kk = 0; kk < 8; ++kk)
            afrag[m][kk] = *reinterpret_cast<const bf16x8*>(
                z + (size_t)(r0 + m*16 + lrow) * D + kk*32 + quad*8);

    float racc[4][4];
#pragma unroll
    for (int m = 0; m < 4; ++m)
#pragma unroll
        for (int j = 0; j < 4; ++j) racc[m][j] = 0.f;

    // Prologue: load tile 0 into registers.
    ushort8 sreg[8];
#pragma unroll
    for (int i = 0; i < 8; ++i) {
        const int L = i * 256 + tid;
        const int r = L >> 5, cl = L & 31;
        sreg[i] = *reinterpret_cast<const ushort8*>(z + (size_t)(cbase + r) * D + cl*8);
    }

    for (int ct = 0; ct < NT; ++ct) {
        const int buf = ct & 1;
        // Commit staged registers to LDS (swizzled). The implicit vmcnt wait for
        // sreg happens here — those loads were issued a full compute-tile ago.
#pragma unroll
        for (int i = 0; i < 8; ++i) {
            const int L = i * 256 + tid;
            const int r = L >> 5, cl = L & 31;
            *reinterpret_cast<ushort8*>(&tb[buf][r * D + (cl ^ (r & 7)) * 8]) = sreg[i];
        }
        __syncthreads();
        // Issue next tile's loads before computing (in flight during MFMA).
        if (ct + 1 < NT) {
            const int c0n = cbase + (ct + 1) * CT;
#pragma unroll
            for (int i = 0; i < 8; ++i) {
                const int L = i * 256 + tid;
                const int r = L >> 5, cl = L & 31;
                sreg[i] = *reinterpret_cast<const ushort8*>(z + (size_t)(c0n + r) * D + cl*8);
            }
        }
        // Compute on tb[buf].
#pragma unroll
        for (int n = 0; n < 4; ++n) {
            bf16x8 bfrag[8];
#pragma unroll
            for (int kk = 0; kk < 8; ++kk) {
                const int r = n*16 + lrow;
                const int cp = (kk*4 + quad) ^ (lrow & 7);
                bfrag[kk] = *reinterpret_cast<const bf16x8*>(&tb[buf][r * D + cp * 8]);
            }
#pragma unroll
            for (int m = 0; m < 4; ++m) {
                f32x4 c = {0.f, 0.f, 0.f, 0.f};
#pragma unroll
                for (int kk = 0; kk < 8; ++kk)
                    c = __builtin_amdgcn_mfma_f32_16x16x32_bf16(afrag[m][kk], bfrag[kk], c, 0, 0, 0);
#pragma unroll
                for (int j = 0; j < 4; ++j)
                    racc[m][j] += __expf(c[j]);
            }
        }
        // No trailing barrier needed: next iteration writes buf^1, which the
        // slowest wave last read two iterations ago (separated by this sync).
        __syncthreads();
    }

    // Row sums live across lanes sharing `quad`; reduce over lane bits 0-3 (the col index).
#pragma unroll
    for (int m = 0; m < 4; ++m)
#pragma unroll
        for (int j = 0; j < 4; ++j) {
            float v = racc[m][j];
            v += __shfl_xor(v, 1);
            v += __shfl_xor(v, 2);
            v += __shfl_xor(v, 4);
            v += __shfl_xor(v, 8);
            if (lrow == 0)
                partial[(size_t)blockIdx.y * R2 + r0 + m*16 + quad*4 + j] = v;
        }
}

// Kernel C: loss_r = log(exp(p_r) + S_r - e^2) - p_r ; out = mean.
__global__ __launch_bounds__(1024) void finalize_kernel(const float* __restrict__ partial,
                                                        const float* __restrict__ pos,
                                                        float* __restrict__ out) {
    __shared__ float wsum[16];
    const int tid = threadIdx.x;
    float lsum = 0.f;
    for (int r = tid; r < R2; r += 1024) {
        float S = 0.f;
#pragma unroll
        for (int s = 0; s < NSPLIT; ++s) S += partial[(size_t)s * R2 + r];
        const float p = pos[r & (BB - 1)];
        lsum += __logf(__expf(p) + S - E2) - p;
    }
#pragma unroll
    for (int off = 32; off; off >>= 1) lsum += __shfl_xor(lsum, off);
    if ((tid & 63) == 0) wsum[tid >> 6] = lsum;
    __syncthreads();
    if (tid == 0) {
        float t = 0.f;
#pragma unroll
        for (int i = 0; i < 16; ++i) t += wsum[i];
        out[0] = t / (float)R2;
    }
}

extern "C" void kernel_launch(void* const* d_in, const int* in_sizes, int n_in,
                              void* d_out, int out_size, void* d_ws, size_t ws_size,
                              hipStream_t stream) {
    (void)in_sizes; (void)n_in; (void)out_size; (void)ws_size;
    const float* xi = (const float*)d_in[0];
    const float* xj = (const float*)d_in[1];
    float* out = (float*)d_out;

    unsigned short* z = (unsigned short*)d_ws;                                   // 8192*256*2 = 4 MB
    float* partial = (float*)((char*)d_ws + (size_t)R2 * D * 2);                 // 16*8192*4 = 512 KB
    float* pos     = (float*)((char*)d_ws + (size_t)R2 * D * 2 + NSPLIT*R2*4);   // 16 KB

    norm_kernel<<<BB / 4, 256, 0, stream>>>(xi, xj, z, pos);
    sim_kernel<<<dim3(R2 / 256, NSPLIT), 256, 0, stream>>>(z, partial);
    finalize_kernel<<<1, 1024, 0, stream>>>(partial, pos, out);
}

// Round 4
// 102.059 us; speedup vs baseline: 1.2119x; 1.2119x over previous
//
#include <hip/hip_runtime.h>
#include <hip/hip_bf16.h>

typedef __attribute__((ext_vector_type(8))) short bf16x8;     // 8 bf16 = 4 VGPRs (MFMA A/B operand)
typedef __attribute__((ext_vector_type(4))) float f32x4;      // MFMA C/D
typedef __attribute__((ext_vector_type(4))) unsigned short ushort4v;

constexpr int BB = 4096;   // batch B
constexpr int D  = 256;    // feature dim
constexpr int R2 = 8192;   // 2B rows of z
constexpr int NSPLIT = 16; // column splits of the sim reduction (512 cols per block)
constexpr int CT = 64;     // columns staged per LDS tile
constexpr int NT = (R2 / NSPLIT) / CT;  // 8 tiles per block
constexpr float SQRT2 = 1.41421356237309515f;
constexpr float E2 = 7.38905609893065f;  // exp(2) == exp(diag sim)

__device__ __forceinline__ unsigned short f2bf(float f) {
    __hip_bfloat16 h = __float2bfloat16(f);
    return *reinterpret_cast<unsigned short*>(&h);
}

// Async 16B/lane global->LDS DMA. Dest is wave-uniform base + lane*16 (HW-fixed).
__device__ __forceinline__ void async16(const unsigned short* g, unsigned short* l) {
    __builtin_amdgcn_global_load_lds(
        (const __attribute__((address_space(1))) void*)g,
        (__attribute__((address_space(3))) void*)l,
        16, 0, 0);
}

// Kernel A: L2-normalize rows, scale by sqrt(2), store bf16 z[8192][256]; pos[k] = 2*cos(xi_k, xj_k).
__global__ __launch_bounds__(256) void norm_kernel(const float* __restrict__ xi,
                                                   const float* __restrict__ xj,
                                                   unsigned short* __restrict__ z,
                                                   float* __restrict__ pos) {
    const int wid = threadIdx.x >> 6, lane = threadIdx.x & 63;
    const int k = blockIdx.x * 4 + wid;
    const float4* a4 = reinterpret_cast<const float4*>(xi + (size_t)k * D);
    const float4* b4 = reinterpret_cast<const float4*>(xj + (size_t)k * D);
    float4 a = a4[lane], b = b4[lane];
    float ssi = a.x*a.x + a.y*a.y + a.z*a.z + a.w*a.w;
    float ssj = b.x*b.x + b.y*b.y + b.z*b.z + b.w*b.w;
    float dot = a.x*b.x + a.y*b.y + a.z*b.z + a.w*b.w;
#pragma unroll
    for (int off = 32; off; off >>= 1) {
        ssi += __shfl_xor(ssi, off);
        ssj += __shfl_xor(ssj, off);
        dot += __shfl_xor(dot, off);
    }
    const float inv_i = 1.0f / fmaxf(sqrtf(ssi), 1e-12f);
    const float inv_j = 1.0f / fmaxf(sqrtf(ssj), 1e-12f);
    const float si = inv_i * SQRT2, sj = inv_j * SQRT2;
    ushort4v zi = { f2bf(a.x*si), f2bf(a.y*si), f2bf(a.z*si), f2bf(a.w*si) };
    ushort4v zj = { f2bf(b.x*sj), f2bf(b.y*sj), f2bf(b.z*sj), f2bf(b.w*sj) };
    *reinterpret_cast<ushort4v*>(z + (size_t)k * D + lane*4)        = zi;
    *reinterpret_cast<ushort4v*>(z + (size_t)(k+BB) * D + lane*4)   = zj;
    if (lane == 0) pos[k] = dot * inv_i * inv_j * 2.0f;
}

// Kernel B: partial[split][r] = sum over this split's 512 columns c of exp(z_r . z_c).
// 4 waves x 64 rows = 256 rows/block; afrag register-resident (128 VGPRs).
// B-tiles (64 cols) double-buffered in unpadded 2x32KB LDS via global_load_lds DMA,
// issued one tile ahead (latency hidden behind MFMA). Bank-conflict-free reads via
// source-address swizzle: pair p at p*1024B, sub-row r1 at +r1*512, chunk c at
// +(c ^ 4*r1)*16 -> read offsets (kk^r1)*64 + quad*16 cover all 8 bank-quarters.
__global__ __launch_bounds__(256, 2) void sim_kernel(const unsigned short* __restrict__ z,
                                                     float* __restrict__ partial) {
    __shared__ unsigned short tb[2][CT * D];   // 2 x 32 KB, unpadded (DMA layout)
    const int tid = threadIdx.x;
    const int wid = tid >> 6, lane = tid & 63;
    const int lrow = lane & 15, quad = lane >> 4;
    const int r0 = blockIdx.x * 256 + wid * 64;       // this wave's 64 rows
    const int cbase = blockIdx.y * (R2 / NSPLIT);

    // Staging source (per-lane, fixed across tiles): half-wave h=lane>>5 picks row
    // parity; source chunk is XOR-swizzled so the forced dest (lane*16) lands it
    // at physical slot (c ^ 4*r1).
    const int half = lane >> 5;
    const int srcchunk = (lane & 31) ^ (half << 2);
    const unsigned short* gstage = z + (size_t)(cbase + wid*16 + half) * D + srcchunk * 8;
    unsigned short* dst0 = &tb[0][wid * 4096];   // this wave's 8 pairs = 8 KB region
    unsigned short* dst1 = &tb[1][wid * 4096];

    // Issue tile-0 DMA first so it overlaps the afrag global loads.
#pragma unroll
    for (int i = 0; i < 8; ++i) async16(gstage + i*512, dst0 + i*512);

    // A fragments: this wave's 64 rows x full K=256 in registers.
    bf16x8 afrag[4][8];
#pragma unroll
    for (int m = 0; m < 4; ++m)
#pragma unroll
        for (int kk = 0; kk < 8; ++kk)
            afrag[m][kk] = *reinterpret_cast<const bf16x8*>(
                z + (size_t)(r0 + m*16 + lrow) * D + kk*32 + quad*8);

    float racc[4][4];
#pragma unroll
    for (int m = 0; m < 4; ++m)
#pragma unroll
        for (int j = 0; j < 4; ++j) racc[m][j] = 0.f;

    // Swizzled read base (shorts): bit 5 of the plain base is 0, so the kk XOR
    // folds: addr = lb2 ^ (kk*32).
    const int r1 = lrow & 1;
    const int lb2 = (((lrow >> 1) * 512) + r1 * 256 + quad * 8) ^ (r1 * 32);

    __syncthreads();   // tile-0 DMA complete (compiler emits vmcnt(0) before barrier)

    for (int ct = 0; ct < NT; ++ct) {
        const unsigned short* tbb = (ct & 1) ? &tb[1][0] : &tb[0][0];
        // Issue next tile's DMA into the other buffer (safe: last read of that
        // buffer was before the previous barrier). Lands during this compute.
        if (ct + 1 < NT) {
            const unsigned short* gs = gstage + (size_t)(ct + 1) * (CT * D);
            unsigned short* dn = (ct & 1) ? dst0 : dst1;
#pragma unroll
            for (int i = 0; i < 8; ++i) async16(gs + i*512, dn + i*512);
        }
#pragma unroll
        for (int n = 0; n < 4; ++n) {
            bf16x8 bfrag[8];
#pragma unroll
            for (int kk = 0; kk < 8; ++kk)
                bfrag[kk] = *reinterpret_cast<const bf16x8*>(&tbb[n*4096 + (lb2 ^ (kk*32))]);
#pragma unroll
            for (int m = 0; m < 4; ++m) {
                f32x4 c = {0.f, 0.f, 0.f, 0.f};
#pragma unroll
                for (int kk = 0; kk < 8; ++kk)
                    c = __builtin_amdgcn_mfma_f32_16x16x32_bf16(afrag[m][kk], bfrag[kk], c, 0, 0, 0);
#pragma unroll
                for (int j = 0; j < 4; ++j)
                    racc[m][j] += __expf(c[j]);
            }
        }
        __syncthreads();   // all waves done reading tbb; next tile's DMA drained
    }

    // Row sums live across lanes sharing `quad`; reduce over lane bits 0-3 (the col index).
#pragma unroll
    for (int m = 0; m < 4; ++m)
#pragma unroll
        for (int j = 0; j < 4; ++j) {
            float v = racc[m][j];
            v += __shfl_xor(v, 1);
            v += __shfl_xor(v, 2);
            v += __shfl_xor(v, 4);
            v += __shfl_xor(v, 8);
            if (lrow == 0)
                partial[(size_t)blockIdx.y * R2 + r0 + m*16 + quad*4 + j] = v;
        }
}

// Kernel C: loss_r = log(exp(p_r) + S_r - e^2) - p_r ; out = mean.
__global__ __launch_bounds__(1024) void finalize_kernel(const float* __restrict__ partial,
                                                        const float* __restrict__ pos,
                                                        float* __restrict__ out) {
    __shared__ float wsum[16];
    const int tid = threadIdx.x;
    float lsum = 0.f;
    for (int r = tid; r < R2; r += 1024) {
        float S = 0.f;
#pragma unroll
        for (int s = 0; s < NSPLIT; ++s) S += partial[(size_t)s * R2 + r];
        const float p = pos[r & (BB - 1)];
        lsum += __logf(__expf(p) + S - E2) - p;
    }
#pragma unroll
    for (int off = 32; off; off >>= 1) lsum += __shfl_xor(lsum, off);
    if ((tid & 63) == 0) wsum[tid >> 6] = lsum;
    __syncthreads();
    if (tid == 0) {
        float t = 0.f;
#pragma unroll
        for (int i = 0; i < 16; ++i) t += wsum[i];
        out[0] = t / (float)R2;
    }
}

extern "C" void kernel_launch(void* const* d_in, const int* in_sizes, int n_in,
                              void* d_out, int out_size, void* d_ws, size_t ws_size,
                              hipStream_t stream) {
    (void)in_sizes; (void)n_in; (void)out_size; (void)ws_size;
    const float* xi = (const float*)d_in[0];
    const float* xj = (const float*)d_in[1];
    float* out = (float*)d_out;

    unsigned short* z = (unsigned short*)d_ws;                                   // 8192*256*2 = 4 MB
    float* partial = (float*)((char*)d_ws + (size_t)R2 * D * 2);                 // 16*8192*4 = 512 KB
    float* pos     = (float*)((char*)d_ws + (size_t)R2 * D * 2 + NSPLIT*R2*4);   // 16 KB

    norm_kernel<<<BB / 4, 256, 0, stream>>>(xi, xj, z, pos);
    sim_kernel<<<dim3(R2 / 256, NSPLIT), 256, 0, stream>>>(z, partial);
    finalize_kernel<<<1, 1024, 0, stream>>>(partial, pos, out);
}